// Round 9
// baseline (165.361 us; speedup 1.0000x reference)
//
#include <hip/hip_runtime.h>
#include <hip/hip_bf16.h>

typedef short bf16x8 __attribute__((ext_vector_type(8)));   // 8 bf16 = 4 VGPRs
typedef float f32x4  __attribute__((ext_vector_type(4)));
typedef float f32x2  __attribute__((ext_vector_type(2)));
typedef unsigned int u32x4 __attribute__((ext_vector_type(4)));

#define SPATIAL 35
#define K1 350
#define KPAD 352          // 11 chunks of 32
#define N1 256
#define TILE_M 64
#define NCHUNK 11
#define HROW 360          // ha row stride in bf16 (45 granules): bank-balanced for b128 r/w

// ---- pre-kernel: w1 [256][350] f32 -> chunk-major bf16 w1t[ch][n][32] ----
__global__ void convert_w1(const float* __restrict__ w1, unsigned short* __restrict__ w1t) {
    int i  = blockIdx.x * 256 + threadIdx.x;    // < 256*352 = 90112
    int kk = i & 31;
    int n  = (i >> 5) & 255;
    int ch = i >> 13;
    int k  = ch * 32 + kk;
    float v = (k < K1) ? w1[n * K1 + k] : 0.f;
    w1t[i] = __builtin_bit_cast(unsigned short, __float2bfloat16(v));
}

static __device__ __forceinline__ unsigned int pack_bf16(float h0, float h1) {
    unsigned int u0 = (unsigned int)__builtin_bit_cast(unsigned short, __float2bfloat16(h0));
    unsigned int u1 = (unsigned int)__builtin_bit_cast(unsigned short, __float2bfloat16(h1));
    return u0 | (u1 << 16);
}

// conv of k-band [K0, K0 + 8*NG) for this lane's sample; all indices compile-time
template<int K0, int NG>
static __device__ __forceinline__ void conv_band(const float* __restrict__ x,
        const float* __restrict__ wa, const float* __restrict__ ba,
        unsigned short* __restrict__ s_ha, int lane) {
    u32x4* row = reinterpret_cast<u32x4*>(s_ha + lane * HROW);   // 45 granules/row
    #pragma unroll
    for (int g = 0; g < NG; ++g) {
        unsigned int dw[4];
        #pragma unroll
        for (int e = 0; e < 4; ++e) {
            const int k0 = K0 + 8 * g + 2 * e;
            const int k1 = k0 + 1;
            float h0 = 0.f, h1 = 0.f;
            if (k0 < K1) {
                const int c = k0 / SPATIAL, ij = k0 % SPATIAL;
                h0 = fmaxf(fmaf(x[ij], wa[c], ba[c]), 0.f);
            }
            if (k1 < K1) {
                const int c = k1 / SPATIAL, ij = k1 % SPATIAL;
                h1 = fmaxf(fmaf(x[ij], wa[c], ba[c]), 0.f);
            }
            dw[e] = pack_bf16(h0, h1);
        }
        row[K0 / 8 + g] = (u32x4){dw[0], dw[1], dw[2], dw[3]};
    }
}

__global__ __launch_bounds__(512, 6)
void fused_actor_critic_mfma8(const float* __restrict__ state,
                              const float* __restrict__ wa, const float* __restrict__ ba,
                              const unsigned short* __restrict__ w1t, const float* __restrict__ b1,
                              const float* __restrict__ w2, const float* __restrict__ b2,
                              const float* __restrict__ wc, const float* __restrict__ bc,
                              const float* __restrict__ wlc, const float* __restrict__ blc,
                              float* __restrict__ out, int batch)
{
    // s_ha doubles as the FC2 partial buffer after the K loop
    __shared__ __align__(16) unsigned short s_ha[TILE_M * HROW];   // 46080 B -> 3 blocks/CU

    const int t    = threadIdx.x;
    const int lane = t & 63;
    const int wave = t >> 6;         // 0..7
    const int lm   = lane & 15;
    const int lq   = lane >> 4;
    const int s_base = blockIdx.x * TILE_M;
    const int n0w  = wave * 32;      // 32 neurons per wave

    // ---- W prefetch depth 4: chunks 0..3 (contiguous 1KB/instr, L2-resident) ----
    bf16x8 wfr[4][2];
    const unsigned short* wrow = w1t + (size_t)(n0w + lm) * 32 + lq * 8;
    #pragma unroll
    for (int c4 = 0; c4 < 4; ++c4)
        #pragma unroll
        for (int nt = 0; nt < 2; ++nt)
            wfr[c4][nt] = *(const bf16x8*)(wrow + (size_t)c4 * 8192 + nt * 512);

    // ---- own sample row straight from global -> registers (no staging, no barrier) ----
    float x[35];
    {
        const float* srow = state + (size_t)(s_base + lane) * SPATIAL;   // 140 B contiguous
        #pragma unroll
        for (int q = 0; q < 8; ++q)
            *reinterpret_cast<f32x4*>(&x[4 * q]) = *reinterpret_cast<const f32x4*>(srow + 4 * q);
        *reinterpret_cast<f32x2*>(&x[32]) = *reinterpret_cast<const f32x2*>(srow + 32);
        x[34] = srow[34];
    }

    // ---- cooperative conv: waves 0-6 own 48-k bands; wave 7: 16-k band + critic ----
    switch (wave) {
        case 0: conv_band<0,   6>(x, wa, ba, s_ha, lane); break;
        case 1: conv_band<48,  6>(x, wa, ba, s_ha, lane); break;
        case 2: conv_band<96,  6>(x, wa, ba, s_ha, lane); break;
        case 3: conv_band<144, 6>(x, wa, ba, s_ha, lane); break;
        case 4: conv_band<192, 6>(x, wa, ba, s_ha, lane); break;
        case 5: conv_band<240, 6>(x, wa, ba, s_ha, lane); break;
        case 6: conv_band<288, 6>(x, wa, ba, s_ha, lane); break;
        default: {
            conv_band<336, 2>(x, wa, ba, s_ha, lane);
            float cv = blc[0];
            #pragma unroll
            for (int ij = 0; ij < SPATIAL; ++ij)
                #pragma unroll
                for (int c = 0; c < 3; ++c)
                    cv = fmaf(wlc[c * SPATIAL + ij], fmaxf(fmaf(x[ij], wc[c], bc[c]), 0.f), cv);
            out[(size_t)5 * batch + s_base + lane] = cv;
            break;
        }
    }
    __syncthreads();     // the single pre-K barrier

    // ---- barrier-free K loop: af depth-1 LDS prefetch, W depth-4 global prefetch ----
    f32x4 acc[2][4];                 // [nt][mt]; neuron = n0w+16nt+4lq+r, sample = 16mt+lm
    #pragma unroll
    for (int nt = 0; nt < 2; ++nt)
        #pragma unroll
        for (int mt = 0; mt < 4; ++mt)
            acc[nt][mt] = (f32x4){0.f, 0.f, 0.f, 0.f};

    const unsigned short* abase = s_ha + lm * HROW + lq * 8;
    bf16x8 afr[2][4];
    #pragma unroll
    for (int mt = 0; mt < 4; ++mt)
        afr[0][mt] = *(const bf16x8*)(abase + mt * 16 * HROW);

    #pragma unroll
    for (int ch = 0; ch < NCHUNK; ++ch) {
        if (ch + 1 < NCHUNK) {
            #pragma unroll
            for (int mt = 0; mt < 4; ++mt)
                afr[(ch + 1) & 1][mt] = *(const bf16x8*)(abase + mt * 16 * HROW + (ch + 1) * 32);
        }
        #pragma unroll
        for (int nt = 0; nt < 2; ++nt)
            #pragma unroll
            for (int mt = 0; mt < 4; ++mt)
                acc[nt][mt] = __builtin_amdgcn_mfma_f32_16x16x32_bf16(
                    wfr[ch & 3][nt], afr[ch & 1][mt], acc[nt][mt], 0, 0, 0);
        if (ch + 4 < NCHUNK) {
            #pragma unroll
            for (int nt = 0; nt < 2; ++nt)
                wfr[ch & 3][nt] = *(const bf16x8*)(wrow + (size_t)(ch + 4) * 8192 + nt * 512);
        }
    }

    // ---- bias + relu ----
    #pragma unroll
    for (int nt = 0; nt < 2; ++nt) {
        f32x4 bv = *(const f32x4*)&b1[n0w + 16 * nt + 4 * lq];
        #pragma unroll
        for (int mt = 0; mt < 4; ++mt)
            #pragma unroll
            for (int r = 0; r < 4; ++r)
                acc[nt][mt][r] = fmaxf(acc[nt][mt][r] + bv[r], 0.f);
    }

    __syncthreads();     // all af reads done; overlay s_ha as FC2 partial buffer
    float* part = reinterpret_cast<float*>(s_ha);    // [wave][m][l] : wave*320 + m*5 + l

    // ---- FC2: reduce over lq (2 shfl steps), partials to overlay ----
    #pragma unroll
    for (int l = 0; l < 5; ++l) {
        f32x4 wv[2];
        #pragma unroll
        for (int nt = 0; nt < 2; ++nt)
            wv[nt] = *(const f32x4*)&w2[l * N1 + n0w + 16 * nt + 4 * lq];
        #pragma unroll
        for (int mt = 0; mt < 4; ++mt) {
            float p = 0.f;
            #pragma unroll
            for (int nt = 0; nt < 2; ++nt)
                #pragma unroll
                for (int r = 0; r < 4; ++r)
                    p = fmaf(acc[nt][mt][r], wv[nt][r], p);
            p += __shfl_xor(p, 16);
            p += __shfl_xor(p, 32);
            bool mine = (l < 4) ? (lq == l) : (lq == 0);
            if (mine) part[wave * 320 + (16 * mt + lm) * 5 + l] = p;
        }
    }
    __syncthreads();

    // ---- final combine ----
    if (t < TILE_M) {
        const int gs = s_base + t;
        #pragma unroll
        for (int l = 0; l < 5; ++l) {
            float v = b2[l];
            #pragma unroll
            for (int w = 0; w < 8; ++w)
                v += part[w * 320 + t * 5 + l];
            out[(size_t)gs * 5 + l] = v;
        }
    }
}

extern "C" void kernel_launch(void* const* d_in, const int* in_sizes, int n_in,
                              void* d_out, int out_size, void* d_ws, size_t ws_size,
                              hipStream_t stream) {
    const float* state = (const float*)d_in[0];
    const float* wa    = (const float*)d_in[1];
    const float* ba    = (const float*)d_in[2];
    const float* w1    = (const float*)d_in[3];
    const float* b1    = (const float*)d_in[4];
    const float* w2    = (const float*)d_in[5];
    const float* b2    = (const float*)d_in[6];
    const float* wc    = (const float*)d_in[7];
    const float* bc    = (const float*)d_in[8];
    const float* wlc   = (const float*)d_in[9];
    const float* blc   = (const float*)d_in[10];
    float* out = (float*)d_out;
    unsigned short* w1t = (unsigned short*)d_ws;            // 180224 B

    int B = in_sizes[0] / SPATIAL;                          // 262144
    hipLaunchKernelGGL(convert_w1, dim3((N1 * KPAD) / 256), dim3(256), 0, stream, w1, w1t);
    hipLaunchKernelGGL(fused_actor_critic_mfma8, dim3(B / TILE_M), dim3(512), 0, stream,
                       state, wa, ba, w1t, b1, w2, b2, wc, bc, wlc, blc, out, B);
}